// Round 1
// baseline (2230.900 us; speedup 1.0000x reference)
//
#include <hip/hip_runtime.h>

// ---------------------------------------------------------------------------
// VQPromptBlock: VQ codebook lookup + 3 residual blocks + 1x1 head
// Round 0: all-fp32 vector implementation (correctness baseline).
// Layout decisions: q kept NHWC fp32 in ws; weights pre-transposed per launch.
// ---------------------------------------------------------------------------

#define NPOS 65536      // B*H*W
#define HW_ 4096
#define CCH 256
#define NTOK 512

// ws float offsets
#define WS_Q      0                       // 16*4096*256 = 16777216  (q NHWC fp32)
#define WS_H1     16777216                // 16*4096*64  = 4194304   (h1 NHWC fp32, relu'd)
#define WS_ET     20971520                // 512*256     = 131072    (embed transposed [t][c])
#define WS_EN     21102592                // 512                      (||e_t||^2)
#define WS_W1T    21103104                // 3*9*256*64  = 442368    (w1t [l][tap][c][oc])
#define WS_W2T    21545472                // 3*64*256    = 49152     (w2t [l][cb][co])
#define WS_DIFF   21594624                // 1                        (diff accumulator)

// ---------------------------------------------------------------------------
// prep: transposes + norms + zeroing of accumulators (runs every launch)
// ---------------------------------------------------------------------------
__global__ __launch_bounds__(256) void prep_kernel(
    const float* __restrict__ embed, const float* __restrict__ w1,
    const float* __restrict__ w2, float* __restrict__ ws, float* __restrict__ wf) {
  int i = blockIdx.x * 256 + threadIdx.x;
  if (i < 131072) {             // embedT[t][c] = embed[c][t]
    int t = i >> 8, c = i & 255;
    ws[WS_ET + i] = embed[c * 512 + t];
  }
  if (i < 512) {                // enorm[t] = sum_c embed[c][t]^2
    float s = 0.f;
    for (int c = 0; c < 256; ++c) { float v = embed[c * 512 + i]; s += v * v; }
    ws[WS_EN + i] = s;
  }
  if (i < 442368) {             // w1t[((l*9+tap)*256+c)*64+oc] = w1[l][oc][c][tap]
    int oc = i & 63; int r = i >> 6; int c = r & 255; r >>= 8;
    int tap = r % 9; int l = r / 9;
    ws[WS_W1T + i] = w1[((l * 64 + oc) * 256 + c) * 9 + tap];
  }
  if (i < 49152) {              // w2t[(l*64+cb)*256+co] = w2[l][co][cb]
    int co = i & 255; int r = i >> 8; int cb = r & 63; int l = r >> 6;
    ws[WS_W2T + i] = w2[(l * 256 + co) * 64 + cb];
  }
  if (i < 8192) wf[i] = 0.f;    // wordfreq region of d_out
  if (i == 0) ws[WS_DIFF] = 0.f;
}

// ---------------------------------------------------------------------------
// dist: per-position argmin over 512 codes; writes q (NHWC), diff, wordfreq.
// Block = 256 threads (4 waves) handles 64 consecutive positions (lane = pos).
// Wave w covers codes [w*128, w*128+128); embed rows fetched via SGPR loads.
// ---------------------------------------------------------------------------
__global__ __launch_bounds__(256) void dist_kernel(
    const float* __restrict__ input, const float* __restrict__ embed,
    float* __restrict__ ws, float* __restrict__ wf) {
  const float* embedT = ws + WS_ET;
  const float* enorm  = ws + WS_EN;
  float* q = ws + WS_Q;
  int blk = blockIdx.x;               // 1024 blocks
  int b   = blk >> 6;                 // 64 blocks per batch
  int hw0 = (blk & 63) << 6;
  int tid  = threadIdx.x;
  int lane = tid & 63;
  int wave = tid >> 6;
  const float* fbase = input + (size_t)b * 256 * 4096 + hw0 + lane;

  float best = 3.4e38f; int bt = 0;
#pragma unroll 1
  for (int tc = 0; tc < 8; ++tc) {
    int t0 = __builtin_amdgcn_readfirstlane(wave * 128 + tc * 16);
    float acc[16];
#pragma unroll
    for (int k = 0; k < 16; ++k) acc[k] = 0.f;
#pragma unroll 1
    for (int cc = 0; cc < 8; ++cc) {
      float f[32];
#pragma unroll
      for (int j = 0; j < 32; ++j) f[j] = fbase[(size_t)(cc * 32 + j) * 4096];
#pragma unroll
      for (int j = 0; j < 32; ++j) {
        const float* er = embed + (cc * 32 + j) * 512 + t0;   // uniform -> s_load
#pragma unroll
        for (int k = 0; k < 16; ++k) acc[k] += f[j] * er[k];
      }
    }
#pragma unroll
    for (int k = 0; k < 16; ++k) {
      float val = enorm[t0 + k] - 2.f * acc[k];
      if (val < best) { best = val; bt = t0 + k; }   // ascending t: first-min kept
    }
  }

  __shared__ float sval[4][64];
  __shared__ int   sidx[4][64];
  __shared__ int   stok[64];
  sval[wave][lane] = best;
  sidx[wave][lane] = bt;
  __syncthreads();
  if (wave == 0) {
    // ||f||^2 for this lane's position (needed for diff = sum of min dists)
    float fn = 0.f;
#pragma unroll 8
    for (int c = 0; c < 256; ++c) { float v = fbase[(size_t)c * 4096]; fn += v * v; }
    float bv = sval[0][lane]; int bi = sidx[0][lane];
#pragma unroll
    for (int w = 1; w < 4; ++w) {
      float v = sval[w][lane]; int t = sidx[w][lane];
      if (v < bv) { bv = v; bi = t; }                // waves ascend in t: ties keep lowest
    }
    stok[lane] = bi;
    atomicAdd(&wf[b * 512 + bi], 1.0f / 4096.0f);    // exact multiples of 2^-12
    float d = fn + bv;                               // true min squared distance
#pragma unroll
    for (int off = 32; off >= 1; off >>= 1) d += __shfl_down(d, off, 64);
    if (lane == 0) atomicAdd(&ws[WS_DIFF], d);
  }
  __syncthreads();
  // epilogue: wave w writes codebook rows for positions [w*16, w*16+16)
#pragma unroll 1
  for (int j = 0; j < 16; ++j) {
    int p = wave * 16 + j;
    int t = __builtin_amdgcn_readfirstlane(stok[p]);
    const float* src = embedT + t * 256;
    float* dst = q + ((size_t)(b * 4096 + hw0 + p)) * 256;
#pragma unroll
    for (int c = 0; c < 4; ++c) dst[c * 64 + lane] = src[c * 64 + lane];
  }
}

// ---------------------------------------------------------------------------
// conv3x3 (+b1, relu in, relu out): q NHWC -> h1 NHWC (64ch).
// Block: batch b x 8x8 spatial tile; thread = (8 oc) x (2 px); c-chunked LDS.
// ---------------------------------------------------------------------------
__global__ __launch_bounds__(256) void conv3x3_kernel(
    const float* __restrict__ qbuf, const float* __restrict__ w1t_all,
    const float* __restrict__ b1, float* __restrict__ h1, int layer) {
  int blk = blockIdx.x;               // 16 b * 64 tiles
  int b = blk >> 6; int tile = blk & 63;
  int ty0 = (tile >> 3) << 3, tx0 = (tile & 7) << 3;
  int tid = threadIdx.x;
  int ocg = tid >> 5;                 // 0..7  -> oc = ocg*8 .. +7
  int pxg = tid & 31;                 // 0..31
  int py  = pxg >> 2;                 // 0..7
  int pxx = (pxg & 3) << 1;           // 0,2,4,6 (two adjacent x per thread)
  const float* w1tl = w1t_all + layer * (9 * 256 * 64);
  float acc0[8], acc1[8];
#pragma unroll
  for (int o = 0; o < 8; ++o) { acc0[o] = 0.f; acc1[o] = 0.f; }
  __shared__ float xs[10 * 10 * 17];  // [pix][c16] padded to 17

#pragma unroll 1
  for (int cc = 0; cc < 16; ++cc) {
    __syncthreads();
#pragma unroll 1
    for (int e = tid; e < 1600; e += 256) {
      int j = e & 15; int pix = e >> 4; int yy = pix / 10; int xx = pix - yy * 10;
      int sy = ty0 + yy - 1, sx = tx0 + xx - 1;
      float v = 0.f;
      if (sy >= 0 && sy < 64 && sx >= 0 && sx < 64)
        v = fmaxf(qbuf[((size_t)(b * 4096 + sy * 64 + sx)) * 256 + cc * 16 + j], 0.f);
      xs[pix * 17 + j] = v;
    }
    __syncthreads();
#pragma unroll 1
    for (int dy = 0; dy < 3; ++dy) {
#pragma unroll 1
      for (int dx = 0; dx < 3; ++dx) {
        int tap = dy * 3 + dx;
        const float* wbase = w1tl + (tap * 256 + cc * 16) * 64 + ocg * 8;
        int xb0 = ((py + dy) * 10 + pxx + dx) * 17;
#pragma unroll
        for (int c = 0; c < 16; ++c) {
          const float4* wv = reinterpret_cast<const float4*>(wbase + c * 64);
          float w[8];
          *reinterpret_cast<float4*>(&w[0]) = wv[0];
          *reinterpret_cast<float4*>(&w[4]) = wv[1];
          float x0 = xs[xb0 + c];
          float x1 = xs[xb0 + 17 + c];
#pragma unroll
          for (int o = 0; o < 8; ++o) { acc0[o] += x0 * w[o]; acc1[o] += x1 * w[o]; }
        }
      }
    }
  }
  int n0 = (ty0 + py) * 64 + tx0 + pxx;
  float* o0 = h1 + ((size_t)(b * 4096 + n0)) * 64 + ocg * 8;
#pragma unroll
  for (int o = 0; o < 8; ++o) {
    float bb = b1[layer * 64 + ocg * 8 + o];
    o0[o]      = fmaxf(acc0[o] + bb, 0.f);
    o0[64 + o] = fmaxf(acc1[o] + bb, 0.f);
  }
}

// ---------------------------------------------------------------------------
// conv1x1 (+b2) + residual add: q[n][co] += sum_cb h1[n][cb]*w2t[cb][co] + b2
// Thread = one pixel; weights uniform -> scalar loads.
// ---------------------------------------------------------------------------
__global__ __launch_bounds__(256) void conv1x1_kernel(
    const float* __restrict__ h1, const float* __restrict__ w2t_all,
    const float* __restrict__ b2, float* __restrict__ qbuf, int layer) {
  int n = blockIdx.x * 256 + threadIdx.x;   // 65536 pixels
  float hv[64];
  const float4* hp = reinterpret_cast<const float4*>(h1 + (size_t)n * 64);
#pragma unroll
  for (int k = 0; k < 16; ++k) {
    float4 v = hp[k];
    hv[4 * k] = v.x; hv[4 * k + 1] = v.y; hv[4 * k + 2] = v.z; hv[4 * k + 3] = v.w;
  }
  const float* w2l = w2t_all + layer * (64 * 256);
  float* qp = qbuf + (size_t)n * 256;
#pragma unroll 1
  for (int cg = 0; cg < 32; ++cg) {
    float a[8];
#pragma unroll
    for (int j = 0; j < 8; ++j) a[j] = b2[layer * 256 + cg * 8 + j];
#pragma unroll
    for (int cb = 0; cb < 64; ++cb) {
      const float* wr = w2l + cb * 256 + cg * 8;   // uniform -> s_load_dwordx8
#pragma unroll
      for (int j = 0; j < 8; ++j) a[j] += hv[cb] * wr[j];
    }
    float4* qv = reinterpret_cast<float4*>(qp + cg * 8);
    float4 q0 = qv[0], q1 = qv[1];
    q0.x += a[0]; q0.y += a[1]; q0.z += a[2]; q0.w += a[3];
    q1.x += a[4]; q1.y += a[5]; q1.z += a[6]; q1.w += a[7];
    qv[0] = q0; qv[1] = q1;
  }
}

// ---------------------------------------------------------------------------
// final 1x1 head -> quant [16][3][64][64] NCHW, plus diff scalar.
// ---------------------------------------------------------------------------
__global__ __launch_bounds__(256) void final_kernel(
    const float* __restrict__ qbuf, const float* __restrict__ ow,
    const float* __restrict__ ob, float* __restrict__ out,
    const float* __restrict__ ws) {
  int n = blockIdx.x * 256 + threadIdx.x;
  const float* qp = qbuf + (size_t)n * 256;
  float a0 = ob[0], a1 = ob[1], a2 = ob[2];
#pragma unroll 8
  for (int c = 0; c < 256; ++c) {
    float v = qp[c];
    a0 += v * ow[c];
    a1 += v * ow[256 + c];
    a2 += v * ow[512 + c];
  }
  int b = n >> 12, hw = n & 4095;
  out[(b * 3 + 0) * 4096 + hw] = a0;
  out[(b * 3 + 1) * 4096 + hw] = a1;
  out[(b * 3 + 2) * 4096 + hw] = a2;
  if (n == 0) out[196608] = ws[WS_DIFF] * (1.0f / 16777216.0f);
}

// ---------------------------------------------------------------------------
extern "C" void kernel_launch(void* const* d_in, const int* in_sizes, int n_in,
                              void* d_out, int out_size, void* d_ws, size_t ws_size,
                              hipStream_t stream) {
  (void)in_sizes; (void)n_in; (void)out_size; (void)ws_size;
  const float* input = (const float*)d_in[0];
  const float* embed = (const float*)d_in[1];
  const float* w1 = (const float*)d_in[2];
  const float* b1 = (const float*)d_in[3];
  const float* w2 = (const float*)d_in[4];
  const float* b2 = (const float*)d_in[5];
  const float* ow = (const float*)d_in[6];
  const float* ob = (const float*)d_in[7];
  float* ws = (float*)d_ws;
  float* out = (float*)d_out;
  float* wf = out + 196609;   // wordfreq region [16][512]

  hipLaunchKernelGGL(prep_kernel, dim3(1728), dim3(256), 0, stream, embed, w1, w2, ws, wf);
  hipLaunchKernelGGL(dist_kernel, dim3(1024), dim3(256), 0, stream, input, embed, ws, wf);
  for (int l = 0; l < 3; ++l) {
    hipLaunchKernelGGL(conv3x3_kernel, dim3(1024), dim3(256), 0, stream,
                       ws + WS_Q, ws + WS_W1T, b1, ws + WS_H1, l);
    hipLaunchKernelGGL(conv1x1_kernel, dim3(256), dim3(256), 0, stream,
                       ws + WS_H1, ws + WS_W2T, b2, ws + WS_Q, l);
  }
  hipLaunchKernelGGL(final_kernel, dim3(256), dim3(256), 0, stream,
                     ws + WS_Q, ow, ob, out, ws);
}

// Round 2
// 723.001 us; speedup vs baseline: 3.0856x; 3.0856x over previous
//
#include <hip/hip_runtime.h>
#include <hip/hip_bf16.h>

// ---------------------------------------------------------------------------
// VQPromptBlock: VQ codebook lookup + 3 residual blocks + 1x1 head
// Round 1: conv3x3 -> bf16 MFMA implicit GEMM (32x32x16), weights fragment-
// packed in ws by prep (reusing old W1T region; bf16 so footprint unchanged).
// dist / conv1x1 / final unchanged from round 0 (isolate the conv3x3 change).
// ---------------------------------------------------------------------------

typedef __attribute__((ext_vector_type(8))) short short8;
typedef __attribute__((ext_vector_type(16))) float f32x16;

// ws float offsets (identical footprint to round 0)
#define WS_Q      0                       // 16*4096*256 f32 (q NHWC)
#define WS_H1     16777216                // 16*4096*64  f32 (h1 NHWC, relu'd)
#define WS_ET     20971520                // 512*256 f32 (embed transposed)
#define WS_EN     21102592                // 512 f32 (||e_t||^2)
#define WS_W1T    21103104                // 442368 bf16 = 221184 f32 slots (wpk)
#define WS_W2T    21545472                // 3*64*256 f32 (w2t [l][cb][co])
#define WS_DIFF   21594624                // 1 f32

__device__ inline short f2bf(float f) {   // RNE float->bf16 bits
  unsigned u = __float_as_uint(f);
  unsigned r = (u + 0x7fffu + ((u >> 16) & 1u)) >> 16;
  return (short)r;
}

// ---------------------------------------------------------------------------
// prep: embed transpose + norms, conv1 weights -> MFMA B-fragment pack (bf16),
// conv2 weights transpose, zero accumulators.
// wpk layout (16B units of 8 bf16): unit = ((layer*9+tap)*16 + k16)*2*64
//   + of*64 + lane ; lane's 8 values = w1[layer][of*32+(lane&31)]
//   [k16*16 + (lane>>5)*8 + j][tap]
// ---------------------------------------------------------------------------
__global__ __launch_bounds__(256) void prep_kernel(
    const float* __restrict__ embed, const float* __restrict__ w1,
    const float* __restrict__ w2, float* __restrict__ ws, float* __restrict__ wf) {
  int i = blockIdx.x * 256 + threadIdx.x;
  if (i < 131072) {             // embedT[t][c] = embed[c][t]
    int t = i >> 8, c = i & 255;
    ws[WS_ET + i] = embed[c * 512 + t];
  }
  if (i < 512) {                // enorm[t]
    float s = 0.f;
    for (int c = 0; c < 256; ++c) { float v = embed[c * 512 + i]; s += v * v; }
    ws[WS_EN + i] = s;
  }
  if (i < 442368) {             // B-fragment pack, bf16
    int j = i & 7; int lane = (i >> 3) & 63; int of = (i >> 9) & 1;
    int k16 = (i >> 10) & 15; int rest = i >> 14;
    int tap = rest % 9; int layer = rest / 9;
    int oc = of * 32 + (lane & 31);
    int c  = k16 * 16 + (lane >> 5) * 8 + j;
    float v = w1[((layer * 64 + oc) * 256 + c) * 9 + tap];
    ((short*)(ws + WS_W1T))[i] = f2bf(v);
  }
  if (i < 49152) {              // w2t[(l*64+cb)*256+co] = w2[l][co][cb]
    int co = i & 255; int r = i >> 8; int cb = r & 63; int l = r >> 6;
    ws[WS_W2T + i] = w2[(l * 256 + co) * 64 + cb];
  }
  if (i < 8192) wf[i] = 0.f;
  if (i == 0) ws[WS_DIFF] = 0.f;
}

// ---------------------------------------------------------------------------
// dist: unchanged from round 0 (fp32; argmin must not move).
// ---------------------------------------------------------------------------
__global__ __launch_bounds__(256) void dist_kernel(
    const float* __restrict__ input, const float* __restrict__ embed,
    float* __restrict__ ws, float* __restrict__ wf) {
  const float* embedT = ws + WS_ET;
  const float* enorm  = ws + WS_EN;
  float* q = ws + WS_Q;
  int blk = blockIdx.x;
  int b   = blk >> 6;
  int hw0 = (blk & 63) << 6;
  int tid  = threadIdx.x;
  int lane = tid & 63;
  int wave = tid >> 6;
  const float* fbase = input + (size_t)b * 256 * 4096 + hw0 + lane;

  float best = 3.4e38f; int bt = 0;
#pragma unroll 1
  for (int tc = 0; tc < 8; ++tc) {
    int t0 = __builtin_amdgcn_readfirstlane(wave * 128 + tc * 16);
    float acc[16];
#pragma unroll
    for (int k = 0; k < 16; ++k) acc[k] = 0.f;
#pragma unroll 1
    for (int cc = 0; cc < 8; ++cc) {
      float f[32];
#pragma unroll
      for (int j = 0; j < 32; ++j) f[j] = fbase[(size_t)(cc * 32 + j) * 4096];
#pragma unroll
      for (int j = 0; j < 32; ++j) {
        const float* er = embed + (cc * 32 + j) * 512 + t0;
#pragma unroll
        for (int k = 0; k < 16; ++k) acc[k] += f[j] * er[k];
      }
    }
#pragma unroll
    for (int k = 0; k < 16; ++k) {
      float val = enorm[t0 + k] - 2.f * acc[k];
      if (val < best) { best = val; bt = t0 + k; }
    }
  }

  __shared__ float sval[4][64];
  __shared__ int   sidx[4][64];
  __shared__ int   stok[64];
  sval[wave][lane] = best;
  sidx[wave][lane] = bt;
  __syncthreads();
  if (wave == 0) {
    float fn = 0.f;
#pragma unroll 8
    for (int c = 0; c < 256; ++c) { float v = fbase[(size_t)c * 4096]; fn += v * v; }
    float bv = sval[0][lane]; int bi = sidx[0][lane];
#pragma unroll
    for (int w = 1; w < 4; ++w) {
      float v = sval[w][lane]; int t = sidx[w][lane];
      if (v < bv) { bv = v; bi = t; }
    }
    stok[lane] = bi;
    atomicAdd(&wf[b * 512 + bi], 1.0f / 4096.0f);
    float d = fn + bv;
#pragma unroll
    for (int off = 32; off >= 1; off >>= 1) d += __shfl_down(d, off, 64);
    if (lane == 0) atomicAdd(&ws[WS_DIFF], d);
  }
  __syncthreads();
#pragma unroll 1
  for (int j = 0; j < 16; ++j) {
    int p = wave * 16 + j;
    int t = __builtin_amdgcn_readfirstlane(stok[p]);
    const float* src = embedT + t * 256;
    float* dst = q + ((size_t)(b * 4096 + hw0 + p)) * 256;
#pragma unroll
    for (int c = 0; c < 4; ++c) dst[c * 64 + lane] = src[c * 64 + lane];
  }
}

// ---------------------------------------------------------------------------
// conv3x3 via bf16 MFMA implicit GEMM.
// Block: 8y x 16x px tile (128 px) x 64 oc. 4 waves: pxh=w&1 (64 px), kh=w>>1
// (half of K). Per 64-ch chunk cs: stage relu(q)->bf16 halo [10y][8cg][18x][8c]
// in LDS; 9 taps x 2 ksteps x 4 mfma_32x32x16. K-halves reduced via LDS.
// ---------------------------------------------------------------------------
__global__ __launch_bounds__(256) void conv3x3_mfma(
    const float* __restrict__ qbuf, const short* __restrict__ wpk,
    const float* __restrict__ b1, float* __restrict__ h1, int layer) {
  __shared__ __align__(16) char smem[32768];
  int blk = blockIdx.x;               // 512 = 16b * 8yt * 4xt
  int b = blk >> 5; int t = blk & 31;
  int ty0 = (t >> 2) << 3;
  int tx0 = (t & 3) << 4;
  int tid = threadIdx.x, lane = tid & 63, w = tid >> 6;
  int pxh = w & 1, kh = w >> 1;
  int xl = lane & 15, ybit = (lane >> 4) & 1, kb = lane >> 5;

  f32x16 acc[2][2];
#pragma unroll
  for (int f = 0; f < 2; ++f)
#pragma unroll
    for (int of = 0; of < 2; ++of)
#pragma unroll
      for (int r = 0; r < 16; ++r) acc[f][of][r] = 0.f;

  const short8* smem8 = (const short8*)smem;
  short8* smem8w = (short8*)smem;
  const short8* wp = (const short8*)wpk + (size_t)layer * 18432;

#pragma unroll 1
  for (int cs = 0; cs < 4; ++cs) {
    __syncthreads();
    // ---- stage 10x18 halo x 64ch: relu + cvt bf16 ----
#pragma unroll 1
    for (int it = 0; it < 6; ++it) {
      int u = tid + it * 256;
      if (u < 1440) {
        int cg = u & 7; int p = u >> 3; int y = p / 18; int x = p - y * 18;
        int sy = ty0 + y - 1, sx = tx0 + x - 1;
        short8 sv;
        if (sy >= 0 && sy < 64 && sx >= 0 && sx < 64) {
          const float* src = qbuf + ((size_t)(b * 4096 + sy * 64 + sx)) * 256 + cs * 64 + cg * 8;
          float4 v0 = *(const float4*)src;
          float4 v1 = *(const float4*)(src + 4);
          sv[0] = f2bf(fmaxf(v0.x, 0.f)); sv[1] = f2bf(fmaxf(v0.y, 0.f));
          sv[2] = f2bf(fmaxf(v0.z, 0.f)); sv[3] = f2bf(fmaxf(v0.w, 0.f));
          sv[4] = f2bf(fmaxf(v1.x, 0.f)); sv[5] = f2bf(fmaxf(v1.y, 0.f));
          sv[6] = f2bf(fmaxf(v1.z, 0.f)); sv[7] = f2bf(fmaxf(v1.w, 0.f));
        } else {
#pragma unroll
          for (int j = 0; j < 8; ++j) sv[j] = 0;
        }
        smem8w[(y * 8 + cg) * 18 + x] = sv;
      }
    }
    __syncthreads();
    // ---- 9 taps x 2 ksteps ----
#pragma unroll 1
    for (int dy = 0; dy < 3; ++dy) {
#pragma unroll 1
      for (int dx = 0; dx < 3; ++dx) {
        int tap = dy * 3 + dx;
#pragma unroll
        for (int ks = 0; ks < 2; ++ks) {
          int cg = kh * 4 + ks * 2 + kb;
          int y0 = 4 * pxh + ybit + dy;
          int a0i = ((y0 * 8 + cg) * 18 + xl + dx);
          short8 A0 = smem8[a0i];
          short8 A1 = smem8[a0i + 2 * 144];      // f=1: +2 halo rows
          int k16 = cs * 4 + kh * 2 + ks;
          int bb = ((tap * 16 + k16) * 2) * 64 + lane;
          short8 B0 = wp[bb];
          short8 B1 = wp[bb + 64];
          acc[0][0] = __builtin_amdgcn_mfma_f32_32x32x16_bf16(A0, B0, acc[0][0], 0, 0, 0);
          acc[0][1] = __builtin_amdgcn_mfma_f32_32x32x16_bf16(A0, B1, acc[0][1], 0, 0, 0);
          acc[1][0] = __builtin_amdgcn_mfma_f32_32x32x16_bf16(A1, B0, acc[1][0], 0, 0, 0);
          acc[1][1] = __builtin_amdgcn_mfma_f32_32x32x16_bf16(A1, B1, acc[1][1], 0, 0, 0);
        }
      }
    }
  }

  // ---- K-half reduce through LDS, then epilogue (bias+relu) ----
  __syncthreads();
  float* smf = (float*)smem;
  if (kh == 1) {
#pragma unroll
    for (int f = 0; f < 2; ++f)
#pragma unroll
      for (int of = 0; of < 2; ++of) {
        float4* d = (float4*)(smf + pxh * 4096 + (f * 2 + of) * 1024 + lane * 16);
#pragma unroll
        for (int r4 = 0; r4 < 4; ++r4) {
          float4 v; v.x = acc[f][of][r4 * 4]; v.y = acc[f][of][r4 * 4 + 1];
          v.z = acc[f][of][r4 * 4 + 2]; v.w = acc[f][of][r4 * 4 + 3];
          d[r4] = v;
        }
      }
  }
  __syncthreads();
  if (kh == 0) {
#pragma unroll
    for (int f = 0; f < 2; ++f)
#pragma unroll
      for (int of = 0; of < 2; ++of) {
        const float* s = smf + pxh * 4096 + (f * 2 + of) * 1024 + lane * 16;
        int oc = of * 32 + (lane & 31);
        float bb = b1[layer * 64 + oc];
#pragma unroll
        for (int r = 0; r < 16; ++r) {
          float v = acc[f][of][r] + s[r] + bb;
          int row = (r & 3) + 8 * (r >> 2) + 4 * kb;
          int y = ty0 + 4 * pxh + 2 * f + (row >> 4);
          int x = tx0 + (row & 15);
          h1[((size_t)(b * 4096 + y * 64 + x)) * 64 + oc] = fmaxf(v, 0.f);
        }
      }
  }
}

// ---------------------------------------------------------------------------
// conv1x1 (+b2) + residual add (unchanged).
// ---------------------------------------------------------------------------
__global__ __launch_bounds__(256) void conv1x1_kernel(
    const float* __restrict__ h1, const float* __restrict__ w2t_all,
    const float* __restrict__ b2, float* __restrict__ qbuf, int layer) {
  int n = blockIdx.x * 256 + threadIdx.x;
  float hv[64];
  const float4* hp = reinterpret_cast<const float4*>(h1 + (size_t)n * 64);
#pragma unroll
  for (int k = 0; k < 16; ++k) {
    float4 v = hp[k];
    hv[4 * k] = v.x; hv[4 * k + 1] = v.y; hv[4 * k + 2] = v.z; hv[4 * k + 3] = v.w;
  }
  const float* w2l = w2t_all + layer * (64 * 256);
  float* qp = qbuf + (size_t)n * 256;
#pragma unroll 1
  for (int cg = 0; cg < 32; ++cg) {
    float a[8];
#pragma unroll
    for (int j = 0; j < 8; ++j) a[j] = b2[layer * 256 + cg * 8 + j];
#pragma unroll
    for (int cb = 0; cb < 64; ++cb) {
      const float* wr = w2l + cb * 256 + cg * 8;
#pragma unroll
      for (int j = 0; j < 8; ++j) a[j] += hv[cb] * wr[j];
    }
    float4* qv = reinterpret_cast<float4*>(qp + cg * 8);
    float4 q0 = qv[0], q1 = qv[1];
    q0.x += a[0]; q0.y += a[1]; q0.z += a[2]; q0.w += a[3];
    q1.x += a[4]; q1.y += a[5]; q1.z += a[6]; q1.w += a[7];
    qv[0] = q0; qv[1] = q1;
  }
}

// ---------------------------------------------------------------------------
// final 1x1 head (unchanged).
// ---------------------------------------------------------------------------
__global__ __launch_bounds__(256) void final_kernel(
    const float* __restrict__ qbuf, const float* __restrict__ ow,
    const float* __restrict__ ob, float* __restrict__ out,
    const float* __restrict__ ws) {
  int n = blockIdx.x * 256 + threadIdx.x;
  const float* qp = qbuf + (size_t)n * 256;
  float a0 = ob[0], a1 = ob[1], a2 = ob[2];
#pragma unroll 8
  for (int c = 0; c < 256; ++c) {
    float v = qp[c];
    a0 += v * ow[c];
    a1 += v * ow[256 + c];
    a2 += v * ow[512 + c];
  }
  int b = n >> 12, hw = n & 4095;
  out[(b * 3 + 0) * 4096 + hw] = a0;
  out[(b * 3 + 1) * 4096 + hw] = a1;
  out[(b * 3 + 2) * 4096 + hw] = a2;
  if (n == 0) out[196608] = ws[WS_DIFF] * (1.0f / 16777216.0f);
}

// ---------------------------------------------------------------------------
extern "C" void kernel_launch(void* const* d_in, const int* in_sizes, int n_in,
                              void* d_out, int out_size, void* d_ws, size_t ws_size,
                              hipStream_t stream) {
  (void)in_sizes; (void)n_in; (void)out_size; (void)ws_size;
  const float* input = (const float*)d_in[0];
  const float* embed = (const float*)d_in[1];
  const float* w1 = (const float*)d_in[2];
  const float* b1 = (const float*)d_in[3];
  const float* w2 = (const float*)d_in[4];
  const float* b2 = (const float*)d_in[5];
  const float* ow = (const float*)d_in[6];
  const float* ob = (const float*)d_in[7];
  float* ws = (float*)d_ws;
  float* out = (float*)d_out;
  float* wf = out + 196609;

  hipLaunchKernelGGL(prep_kernel, dim3(1728), dim3(256), 0, stream, embed, w1, w2, ws, wf);
  hipLaunchKernelGGL(dist_kernel, dim3(1024), dim3(256), 0, stream, input, embed, ws, wf);
  for (int l = 0; l < 3; ++l) {
    hipLaunchKernelGGL(conv3x3_mfma, dim3(512), dim3(256), 0, stream,
                       ws + WS_Q, (const short*)(ws + WS_W1T), b1, ws + WS_H1, l);
    hipLaunchKernelGGL(conv1x1_kernel, dim3(256), dim3(256), 0, stream,
                       ws + WS_H1, ws + WS_W2T, b2, ws + WS_Q, l);
  }
  hipLaunchKernelGGL(final_kernel, dim3(256), dim3(256), 0, stream,
                     ws + WS_Q, ow, ob, out, ws);
}

// Round 3
// 290.723 us; speedup vs baseline: 7.6736x; 2.4869x over previous
//
#include <hip/hip_runtime.h>

// ---------------------------------------------------------------------------
// VQPromptBlock round 2:
//  - dist -> bf16x2-split MFMA (3 passes) + margin-gated exact fp32 redo
//  - q trunk stored bf16, ping-pong buffers; conv1x1 fused into conv3x3 kernel
// ---------------------------------------------------------------------------

typedef __attribute__((ext_vector_type(8))) short short8;
typedef __attribute__((ext_vector_type(16))) float f32x16;
typedef unsigned short ushort_t;
typedef unsigned long long u64;

// ws float offsets
#define WS_QA    0           // q ping: 16*4096*256 bf16 = 8388608 fl
#define WS_QB    8388608     // q pong
#define WS_ET    16777216    // embedT bf16 [512][256]
#define WS_EN    16842752    // enorm fp32 [512]
#define WS_EPK   16843264    // embed frag pack hi/lo: 262144 bf16
#define WS_W1PK  16974336    // w1 frag pack: 442368 bf16
#define WS_W2PK  17195520    // w2 frag pack: 49152 bf16
#define WS_DIFF  17220096    // 1 fl

#define MARGIN 0.0625f

__device__ inline ushort_t f2bf(float f) {
  unsigned u = __float_as_uint(f);
  return (ushort_t)((u + 0x7fffu + ((u >> 16) & 1u)) >> 16);
}
__device__ inline float bf2f(ushort_t h) { return __uint_as_float(((unsigned)h) << 16); }

// ---------------------------------------------------------------------------
// prep: transposes, norms, fragment packs, zeroing.
// ---------------------------------------------------------------------------
__global__ __launch_bounds__(256) void prep_kernel(
    const float* __restrict__ embed, const float* __restrict__ w1,
    const float* __restrict__ w2, float* __restrict__ ws, float* __restrict__ wf) {
  int i = blockIdx.x * 256 + threadIdx.x;
  if (i < 131072) {             // embedT bf16 [t][c]
    int t = i >> 8, c = i & 255;
    ((ushort_t*)(ws + WS_ET))[i] = f2bf(embed[c * 512 + t]);
  }
  if (i < 512) {                // enorm fp32
    float s = 0.f;
    for (int c = 0; c < 256; ++c) { float v = embed[c * 512 + i]; s += v * v; }
    ws[WS_EN + i] = s;
  }
  if (i < 262144) {             // epk[hl][ks16][at16][lane][8]: code=at*32+(lane&31), c=ks*16+(lane>>5)*8+j
    int j = i & 7, lane = (i >> 3) & 63, at = (i >> 9) & 15, ks = (i >> 13) & 15, hl = (i >> 17) & 1;
    int code = at * 32 + (lane & 31);
    int c = ks * 16 + (lane >> 5) * 8 + j;
    float v = embed[c * 512 + code];
    ushort_t h = f2bf(v);
    ((ushort_t*)(ws + WS_EPK))[i] = hl ? f2bf(v - bf2f(h)) : h;
  }
  if (i < 442368) {             // w1pk (round-1 layout)
    int j = i & 7; int lane = (i >> 3) & 63; int of = (i >> 9) & 1;
    int k16 = (i >> 10) & 15; int rest = i >> 14;
    int tap = rest % 9; int layer = rest / 9;
    int oc = of * 32 + (lane & 31);
    int c = k16 * 16 + (lane >> 5) * 8 + j;
    ((ushort_t*)(ws + WS_W1PK))[i] = f2bf(w1[((layer * 64 + oc) * 256 + c) * 9 + tap]);
  }
  if (i < 49152) {              // w2pk[l][ks4][at8][lane][8]: co=at*32+(lane&31), cb=ks*16+(lane>>5)*8+j
    int j = i & 7, lane = (i >> 3) & 63, at = (i >> 9) & 7, ks = (i >> 12) & 3, l = i >> 14;
    int co = at * 32 + (lane & 31), cb = ks * 16 + (lane >> 5) * 8 + j;
    ((ushort_t*)(ws + WS_W2PK))[i] = f2bf(w2[(l * 256 + co) * 64 + cb]);
  }
  if (i < 8192) wf[i] = 0.f;
  if (i == 0) ws[WS_DIFF] = 0.f;
}

// ---------------------------------------------------------------------------
// dist: bf16x2-split MFMA distances + margin-gated exact redo.
// Block: 256 thr, 64 positions. A=codes (epk global frags), B=f (LDS hi/lo).
// Wave w covers codes [128w,128w+128) = 4 A-tiles; 2 B-tiles (pos halves).
// ---------------------------------------------------------------------------
__global__ __launch_bounds__(256, 2) void dist_kernel(
    const float* __restrict__ input, const float* __restrict__ embed,
    const ushort_t* __restrict__ epk, const ushort_t* __restrict__ embedT,
    const float* __restrict__ enorm, float* __restrict__ diffp,
    float* __restrict__ wf, ushort_t* __restrict__ qout) {
  __shared__ __align__(16) char arena[71680];
  ushort_t* fhi = (ushort_t*)arena;              // [64][264]
  ushort_t* flo = (ushort_t*)(arena + 33792);    // [64][264]
  float* senorm = (float*)(arena + 67584);       // 512
  float* sfn    = (float*)(arena + 69632);       // [4][64]
  int*   stok   = (int*)(arena + 70656);         // 64
  float* sdist  = (float*)(arena + 70912);       // 64
  float* sfnt   = (float*)(arena + 71168);       // 64
  u64*   smask  = (u64*)(arena + 71424);
  // overlays, live only after GEMM (fhi/flo dead):
  float* trim1 = (float*)arena;                  // [64][4]
  float* trim2 = (float*)(arena + 1024);
  int*   trii  = (int*)(arena + 2048);
  float* sf    = (float*)(arena + 4096);         // 256 (exact f for redo)
  float* rv    = (float*)(arena + 8192);         // 256
  int*   ri    = (int*)(arena + 9216);           // 256

  int blk = blockIdx.x;
  int b = blk >> 6;
  int hw0 = (blk & 63) << 6;
  int tid = threadIdx.x, lane = tid & 63, wave = tid >> 6;

  for (int i = tid; i < 512; i += 256) senorm[i] = enorm[i];

  // ---- stage f -> hi/lo bf16 LDS [pos][264]; fn partials ----
  const float* ibase = input + (size_t)(b * 256) * 4096 + hw0 + lane;
  float fnacc = 0.f;
#pragma unroll 1
  for (int it = 0; it < 16; ++it) {
    int c0 = it * 16 + wave * 4;
    float v0 = ibase[(size_t)(c0 + 0) * 4096];
    float v1 = ibase[(size_t)(c0 + 1) * 4096];
    float v2 = ibase[(size_t)(c0 + 2) * 4096];
    float v3 = ibase[(size_t)(c0 + 3) * 4096];
    fnacc += v0 * v0 + v1 * v1 + v2 * v2 + v3 * v3;
    ushort_t h0 = f2bf(v0), h1 = f2bf(v1), h2 = f2bf(v2), h3 = f2bf(v3);
    ushort_t l0 = f2bf(v0 - bf2f(h0)), l1 = f2bf(v1 - bf2f(h1));
    ushort_t l2 = f2bf(v2 - bf2f(h2)), l3 = f2bf(v3 - bf2f(h3));
    u64 hh = (u64)h0 | ((u64)h1 << 16) | ((u64)h2 << 32) | ((u64)h3 << 48);
    u64 ll = (u64)l0 | ((u64)l1 << 16) | ((u64)l2 << 32) | ((u64)l3 << 48);
    *(u64*)(fhi + (size_t)lane * 264 + c0) = hh;
    *(u64*)(flo + (size_t)lane * 264 + c0) = ll;
  }
  sfn[wave * 64 + lane] = fnacc;
  __syncthreads();

  // ---- GEMM: 3-pass split, acc[bt][a] ----
  f32x16 acc[2][4];
#pragma unroll
  for (int bt = 0; bt < 2; ++bt)
#pragma unroll
    for (int a = 0; a < 4; ++a)
#pragma unroll
      for (int r = 0; r < 16; ++r) acc[bt][a][r] = 0.f;

  const short8* ep8 = (const short8*)epk;
  int cbase = (lane >> 5) * 8;
#pragma unroll 2
  for (int ks = 0; ks < 16; ++ks) {
    int coff = ks * 16 + cbase;
    short8 bh0 = *(const short8*)(fhi + (lane & 31) * 264 + coff);
    short8 bh1 = *(const short8*)(fhi + ((lane & 31) + 32) * 264 + coff);
    short8 bl0 = *(const short8*)(flo + (lane & 31) * 264 + coff);
    short8 bl1 = *(const short8*)(flo + ((lane & 31) + 32) * 264 + coff);
#pragma unroll
    for (int a = 0; a < 4; ++a) {
      int at = wave * 4 + a;
      short8 ah = ep8[(ks * 16 + at) * 64 + lane];
      short8 al = ep8[((16 + ks) * 16 + at) * 64 + lane];
      acc[0][a] = __builtin_amdgcn_mfma_f32_32x32x16_bf16(ah, bh0, acc[0][a], 0, 0, 0);
      acc[0][a] = __builtin_amdgcn_mfma_f32_32x32x16_bf16(ah, bl0, acc[0][a], 0, 0, 0);
      acc[0][a] = __builtin_amdgcn_mfma_f32_32x32x16_bf16(al, bh0, acc[0][a], 0, 0, 0);
      acc[1][a] = __builtin_amdgcn_mfma_f32_32x32x16_bf16(ah, bh1, acc[1][a], 0, 0, 0);
      acc[1][a] = __builtin_amdgcn_mfma_f32_32x32x16_bf16(ah, bl1, acc[1][a], 0, 0, 0);
      acc[1][a] = __builtin_amdgcn_mfma_f32_32x32x16_bf16(al, bh1, acc[1][a], 0, 0, 0);
    }
  }
  __syncthreads();   // fhi/flo dead; overlays now safe

  // ---- per-wave min/2nd-min over its 128 codes, both pos-tiles ----
  int hi5 = lane >> 5;
#pragma unroll
  for (int bt = 0; bt < 2; ++bt) {
    float m1 = 3.4e38f, m2 = 3.4e38f; int i1 = 0;
#pragma unroll
    for (int a = 0; a < 4; ++a)
#pragma unroll
      for (int r = 0; r < 16; ++r) {
        int code = (wave * 4 + a) * 32 + (r & 3) + 8 * (r >> 2) + 4 * hi5;
        float v = senorm[code] - 2.0f * acc[bt][a][r];
        if (v < m1) { m2 = m1; m1 = v; i1 = code; }
        else if (v < m2) m2 = v;
      }
    float o1 = __shfl_xor(m1, 32, 64);
    float o2 = __shfl_xor(m2, 32, 64);
    int   oi = __shfl_xor(i1, 32, 64);
    float n2 = fminf(fmaxf(m1, o1), fminf(m2, o2));
    float n1 = fminf(m1, o1);
    int   ni = (o1 < m1) ? oi : i1;
    if (lane < 32) {
      int p = bt * 32 + lane;
      trim1[p * 4 + wave] = n1; trim2[p * 4 + wave] = n2; trii[p * 4 + wave] = ni;
    }
  }
  __syncthreads();

  // ---- wave0: final merge, flag mask ----
  if (wave == 0) {
    int p = lane;
    float m1 = trim1[p * 4], m2 = trim2[p * 4]; int i1 = trii[p * 4];
#pragma unroll
    for (int w = 1; w < 4; ++w) {
      float a1 = trim1[p * 4 + w], a2 = trim2[p * 4 + w]; int ai = trii[p * 4 + w];
      float n2 = fminf(fmaxf(m1, a1), fminf(m2, a2));
      if (a1 < m1) { m1 = a1; i1 = ai; }
      m2 = n2;
    }
    float fnt = sfn[p] + sfn[64 + p] + sfn[128 + p] + sfn[192 + p];
    sfnt[p] = fnt; stok[p] = i1; sdist[p] = fnt + m1;
    u64 mk = __ballot(m2 - m1 < MARGIN);
    if (lane == 0) smask[0] = mk;
  }
  __syncthreads();

  // ---- exact fp32 redo for flagged positions ----
  u64 mask = smask[0];
  while (mask) {
    int p = __ffsll(mask) - 1; mask &= mask - 1;
    sf[tid] = input[((size_t)(b * 256 + tid)) * 4096 + hw0 + p];
    __syncthreads();
    float d0 = 0.f, d1 = 0.f;
#pragma unroll 4
    for (int c = 0; c < 256; ++c) {
      float fv = sf[c];
      d0 += fv * embed[c * 512 + tid];
      d1 += fv * embed[c * 512 + 256 + tid];
    }
    float v0 = senorm[tid] - 2.f * d0;
    float v1 = senorm[256 + tid] - 2.f * d1;
    float bv; int bi;
    if (v1 < v0) { bv = v1; bi = 256 + tid; } else { bv = v0; bi = tid; }
    rv[tid] = bv; ri[tid] = bi;
    __syncthreads();
    for (int s = 128; s > 0; s >>= 1) {
      if (tid < s) {
        float ov = rv[tid + s]; int oi2 = ri[tid + s];
        if (ov < rv[tid] || (ov == rv[tid] && oi2 < ri[tid])) { rv[tid] = ov; ri[tid] = oi2; }
      }
      __syncthreads();
    }
    if (tid == 0) { stok[p] = ri[0]; sdist[p] = sfnt[p] + rv[0]; }
    __syncthreads();
  }

  // ---- wordfreq + diff ----
  if (wave == 0) {
    atomicAdd(&wf[b * 512 + stok[lane]], 1.0f / 4096.0f);
    float d = sdist[lane];
#pragma unroll
    for (int off = 32; off >= 1; off >>= 1) d += __shfl_down(d, off, 64);
    if (lane == 0) atomicAdd(diffp, d);
  }
  __syncthreads();

  // ---- q write (bf16 codebook rows) ----
#pragma unroll 1
  for (int j = 0; j < 16; ++j) {
    int p = wave * 16 + j;
    int t = __builtin_amdgcn_readfirstlane(stok[p]);
    const u64* src = (const u64*)(embedT + (size_t)t * 256);
    u64* dst = (u64*)(qout + ((size_t)(b * 4096 + hw0 + p)) * 256);
    dst[lane] = src[lane];
  }
}

// ---------------------------------------------------------------------------
// fused residual layer: relu -> conv3x3(+b1,relu) -> conv1x1(+b2) -> +q
// qin/qout bf16 NHWC (ping-pong). Block: 8y x 16x x 64oc, 4 waves.
// GEMM1: pxh=w&1, kh=w>>1 (K-split, LDS reduce). GEMM2: co-split 4-way.
// ---------------------------------------------------------------------------
__global__ __launch_bounds__(256, 2) void fused_layer(
    const ushort_t* __restrict__ qin, ushort_t* __restrict__ qout,
    const ushort_t* __restrict__ w1pk, const float* __restrict__ b1,
    const ushort_t* __restrict__ w2pk, const float* __restrict__ b2, int l) {
  __shared__ __align__(16) char arena[68608];
  short8* stg = (short8*)arena;                    // 1440 units (GEMM1 staging)
  float* smf = (float*)arena;                      // 8192 fl (K-reduce, after staging)
  ushort_t* hbuf = (ushort_t*)(arena + 32768);     // [128][72] bf16 h tile
  ushort_t* qtile = (ushort_t*)arena;              // [128][264] bf16 h2 tile (after GEMM2)
  float* sb2 = (float*)(arena + 67584);            // 256

  int blk = blockIdx.x;                            // 512 = 16b*8yt*4xt
  int b = blk >> 5; int t = blk & 31;
  int ty0 = (t >> 2) << 3;
  int tx0 = (t & 3) << 4;
  int tid = threadIdx.x, lane = tid & 63, w = tid >> 6;
  int pxh = w & 1, kh = w >> 1;
  int xl = lane & 15, ybit = (lane >> 4) & 1, kb = lane >> 5;

  if (tid < 256) sb2[tid] = b2[l * 256 + tid];

  f32x16 acc[2][2];
#pragma unroll
  for (int f = 0; f < 2; ++f)
#pragma unroll
    for (int of = 0; of < 2; ++of)
#pragma unroll
      for (int r = 0; r < 16; ++r) acc[f][of][r] = 0.f;

  const short8* wp = (const short8*)w1pk + (size_t)l * 18432;

#pragma unroll 1
  for (int cs = 0; cs < 4; ++cs) {
    __syncthreads();
#pragma unroll 1
    for (int e = 0; e < 6; ++e) {
      int u = tid + e * 256;
      if (u < 1440) {
        int cg = u & 7; int pp = u >> 3; int yy = pp / 18; int xx = pp - yy * 18;
        int sy = ty0 + yy - 1, sx = tx0 + xx - 1;
        short8 sv;
        if (sy >= 0 && sy < 64 && sx >= 0 && sx < 64) {
          sv = *(const short8*)(qin + ((size_t)(b * 4096 + sy * 64 + sx)) * 256 + cs * 64 + cg * 8);
#pragma unroll
          for (int k2 = 0; k2 < 8; ++k2) if (sv[k2] < 0) sv[k2] = 0;   // bf16 relu on sign bit
        } else {
#pragma unroll
          for (int k2 = 0; k2 < 8; ++k2) sv[k2] = 0;
        }
        stg[(yy * 8 + cg) * 18 + xx] = sv;
      }
    }
    __syncthreads();
#pragma unroll 1
    for (int dy = 0; dy < 3; ++dy) {
#pragma unroll 1
      for (int dx = 0; dx < 3; ++dx) {
        int tap = dy * 3 + dx;
#pragma unroll
        for (int ks = 0; ks < 2; ++ks) {
          int cg = kh * 4 + ks * 2 + kb;
          int y0 = 4 * pxh + ybit + dy;
          int a0i = (y0 * 8 + cg) * 18 + xl + dx;
          short8 A0 = stg[a0i];
          short8 A1 = stg[a0i + 288];
          int k16 = cs * 4 + kh * 2 + ks;
          int bb = (tap * 16 + k16) * 2 * 64 + lane;
          short8 B0 = wp[bb];
          short8 B1 = wp[bb + 64];
          acc[0][0] = __builtin_amdgcn_mfma_f32_32x32x16_bf16(A0, B0, acc[0][0], 0, 0, 0);
          acc[0][1] = __builtin_amdgcn_mfma_f32_32x32x16_bf16(A0, B1, acc[0][1], 0, 0, 0);
          acc[1][0] = __builtin_amdgcn_mfma_f32_32x32x16_bf16(A1, B0, acc[1][0], 0, 0, 0);
          acc[1][1] = __builtin_amdgcn_mfma_f32_32x32x16_bf16(A1, B1, acc[1][1], 0, 0, 0);
        }
      }
    }
  }

  // ---- K-half reduce ----
  __syncthreads();
  if (kh == 1) {
#pragma unroll
    for (int f = 0; f < 2; ++f)
#pragma unroll
      for (int of = 0; of < 2; ++of) {
        float4* d = (float4*)(smf + pxh * 4096 + (f * 2 + of) * 1024 + lane * 16);
#pragma unroll
        for (int r4 = 0; r4 < 4; ++r4) {
          float4 v; v.x = acc[f][of][r4 * 4]; v.y = acc[f][of][r4 * 4 + 1];
          v.z = acc[f][of][r4 * 4 + 2]; v.w = acc[f][of][r4 * 4 + 3];
          d[r4] = v;
        }
      }
  }
  __syncthreads();
  // ---- bias + relu -> h tile bf16 in LDS (kh=0 waves) ----
  int hi5 = lane >> 5;
  if (kh == 0) {
#pragma unroll
    for (int f = 0; f < 2; ++f)
#pragma unroll
      for (int of = 0; of < 2; ++of) {
        const float* s = smf + pxh * 4096 + (f * 2 + of) * 1024 + lane * 16;
        int oc = of * 32 + (lane & 31);
        float bb = b1[l * 64 + oc];
#pragma unroll
        for (int r = 0; r < 16; ++r) {
          float v = fmaxf(acc[f][of][r] + s[r] + bb, 0.f);
          int row = (r & 3) + 8 * (r >> 2) + 4 * kb;
          int pos = (4 * pxh + 2 * f + (row >> 4)) * 16 + (row & 15);
          hbuf[pos * 72 + oc] = f2bf(v);
        }
      }
  }
  __syncthreads();

  // ---- GEMM2: h[128x64] x w2[64x256], co split 4-way ----
  f32x16 acc2[4][2];
#pragma unroll
  for (int bt = 0; bt < 4; ++bt)
#pragma unroll
    for (int at = 0; at < 2; ++at)
#pragma unroll
      for (int r = 0; r < 16; ++r) acc2[bt][at][r] = 0.f;

  const short8* w2p = (const short8*)w2pk;
#pragma unroll
  for (int ks = 0; ks < 4; ++ks) {
    short8 bfr[4];
#pragma unroll
    for (int bt = 0; bt < 4; ++bt)
      bfr[bt] = *(const short8*)(hbuf + (bt * 32 + (lane & 31)) * 72 + ks * 16 + hi5 * 8);
#pragma unroll
    for (int at = 0; at < 2; ++at) {
      short8 afr = w2p[((l * 4 + ks) * 8 + (w * 2 + at)) * 64 + lane];
#pragma unroll
      for (int bt = 0; bt < 4; ++bt)
        acc2[bt][at] = __builtin_amdgcn_mfma_f32_32x32x16_bf16(afr, bfr[bt], acc2[bt][at], 0, 0, 0);
    }
  }
  __syncthreads();   // h reads done; qtile may overwrite

  // ---- h2 + b2 -> qtile bf16 ----
#pragma unroll
  for (int bt = 0; bt < 4; ++bt) {
    int pos = bt * 32 + (lane & 31);
#pragma unroll
    for (int at = 0; at < 2; ++at) {
#pragma unroll
      for (int g = 0; g < 4; ++g) {
        int co = w * 64 + at * 32 + 8 * g + 4 * hi5;
        u64 pk = 0;
#pragma unroll
        for (int k2 = 0; k2 < 4; ++k2) {
          float v = acc2[bt][at][4 * g + k2] + sb2[co + k2];
          pk |= ((u64)f2bf(v)) << (16 * k2);
        }
        *(u64*)(qtile + pos * 264 + co) = pk;
      }
    }
  }
  __syncthreads();

  // ---- residual add + coalesced store ----
#pragma unroll 1
  for (int it = 0; it < 16; ++it) {
    int px = it * 8 + (tid >> 5);
    int c8 = tid & 31;
    int gy = ty0 + (px >> 4), gx = tx0 + (px & 15);
    size_t gidx = ((size_t)(b * 4096 + gy * 64 + gx)) * 256 + c8 * 8;
    short8 hv = *(const short8*)(qtile + px * 264 + c8 * 8);
    short8 qv = *(const short8*)(qin + gidx);
    short8 ov;
#pragma unroll
    for (int k2 = 0; k2 < 8; ++k2)
      ov[k2] = (short)f2bf(bf2f((ushort_t)qv[k2]) + bf2f((ushort_t)hv[k2]));
    *(short8*)(qout + gidx) = ov;
  }
}

// ---------------------------------------------------------------------------
// final 1x1 head (q bf16 -> fp32 out) + diff scalar
// ---------------------------------------------------------------------------
__global__ __launch_bounds__(256) void final_kernel(
    const ushort_t* __restrict__ qbuf, const float* __restrict__ ow,
    const float* __restrict__ ob, float* __restrict__ out,
    const float* __restrict__ ws) {
  int n = blockIdx.x * 256 + threadIdx.x;
  const ushort_t* qp = qbuf + (size_t)n * 256;
  float a0 = ob[0], a1 = ob[1], a2 = ob[2];
#pragma unroll 4
  for (int cc = 0; cc < 32; ++cc) {
    short8 v = *(const short8*)(qp + cc * 8);
#pragma unroll
    for (int k2 = 0; k2 < 8; ++k2) {
      float f = bf2f((ushort_t)v[k2]);
      int c = cc * 8 + k2;
      a0 += f * ow[c];
      a1 += f * ow[256 + c];
      a2 += f * ow[512 + c];
    }
  }
  int b = n >> 12, hw = n & 4095;
  out[(b * 3 + 0) * 4096 + hw] = a0;
  out[(b * 3 + 1) * 4096 + hw] = a1;
  out[(b * 3 + 2) * 4096 + hw] = a2;
  if (n == 0) out[196608] = ws[WS_DIFF] * (1.0f / 16777216.0f);
}

// ---------------------------------------------------------------------------
extern "C" void kernel_launch(void* const* d_in, const int* in_sizes, int n_in,
                              void* d_out, int out_size, void* d_ws, size_t ws_size,
                              hipStream_t stream) {
  (void)in_sizes; (void)n_in; (void)out_size; (void)ws_size;
  const float* input = (const float*)d_in[0];
  const float* embed = (const float*)d_in[1];
  const float* b1 = (const float*)d_in[3];
  const float* b2 = (const float*)d_in[5];
  const float* ow = (const float*)d_in[6];
  const float* ob = (const float*)d_in[7];
  float* ws = (float*)d_ws;
  float* out = (float*)d_out;
  float* wf = out + 196609;

  ushort_t* qA = (ushort_t*)(ws + WS_QA);
  ushort_t* qB = (ushort_t*)(ws + WS_QB);
  const ushort_t* et = (const ushort_t*)(ws + WS_ET);
  const ushort_t* epk = (const ushort_t*)(ws + WS_EPK);
  const ushort_t* w1pk = (const ushort_t*)(ws + WS_W1PK);
  const ushort_t* w2pk = (const ushort_t*)(ws + WS_W2PK);

  hipLaunchKernelGGL(prep_kernel, dim3(1728), dim3(256), 0, stream,
                     embed, (const float*)d_in[2], (const float*)d_in[4], ws, wf);
  hipLaunchKernelGGL(dist_kernel, dim3(1024), dim3(256), 0, stream,
                     input, embed, epk, et, ws + WS_EN, ws + WS_DIFF, wf, qA);
  hipLaunchKernelGGL(fused_layer, dim3(512), dim3(256), 0, stream,
                     qA, qB, w1pk, b1, w2pk, b2, 0);
  hipLaunchKernelGGL(fused_layer, dim3(512), dim3(256), 0, stream,
                     qB, qA, w1pk, b1, w2pk, b2, 1);
  hipLaunchKernelGGL(fused_layer, dim3(512), dim3(256), 0, stream,
                     qA, qB, w1pk, b1, w2pk, b2, 2);
  hipLaunchKernelGGL(final_kernel, dim3(256), dim3(256), 0, stream,
                     qB, ow, ob, out, ws);
}